// Round 2
// baseline (247.789 us; speedup 1.0000x reference)
//
#include <hip/hip_runtime.h>
#include <hip/hip_bf16.h>
#include <stdint.h>

typedef unsigned short u16;
typedef __attribute__((ext_vector_type(8))) short short8_t;
typedef __attribute__((ext_vector_type(4))) float f32x4;

#define D_DIM 512
#define K_CL  256
#define BM    64
#define NITER 16   // D_DIM / 32

__device__ __forceinline__ u16 f2bf(float f) {
  union { float f; uint32_t u; } v; v.f = f;
  uint32_t r = v.u + 0x7fffu + ((v.u >> 16) & 1u);  // RNE
  return (u16)(r >> 16);
}

// prep: clusters fp32 [256][512] -> bf16 cb [256][512] + csq[256] (fp32 norms)
__global__ void prep_kernel(const float* __restrict__ clusters,
                            u16* __restrict__ cb, float* __restrict__ csq) {
  int k = blockIdx.x;
  int t = threadIdx.x;  // 128 threads, 4 floats each
  float4 f = ((const float4*)(clusters + (size_t)k * D_DIM))[t];
  ushort4 u;
  u.x = f2bf(f.x); u.y = f2bf(f.y); u.z = f2bf(f.z); u.w = f2bf(f.w);
  ((ushort4*)(cb + (size_t)k * D_DIM))[t] = u;
  float s = f.x*f.x + f.y*f.y + f.z*f.z + f.w*f.w;
  #pragma unroll
  for (int m = 1; m < 64; m <<= 1) s += __shfl_xor(s, m, 64);
  __shared__ float part[2];
  if ((t & 63) == 0) part[t >> 6] = s;
  __syncthreads();
  if (t == 0) csq[k] = part[0] + part[1];
}

// main: 64-row x 256-col tile per block, 4 waves (wave w owns cols w*64..w*64+63).
// Pipelined K-loop: one barrier/iter, B(k+1) async->LDS dbuf, x(k+2) reg prefetch,
// x(k+1) converted+written after MFMA. XOR-swizzled LDS chunk slots (2-way banks).
__global__ __launch_bounds__(256)
void cluster_kernel(const float* __restrict__ x,
                    const u16* __restrict__ cb,
                    const float* __restrict__ csq,
                    float* __restrict__ out) {
  // lA: 2 x [64 rows][32 k] bf16 = 2 x 4 KB ; lB: 2 x [256 cols][32 k] bf16 = 2 x 16 KB
  __shared__ __align__(16) char smem[8192 + 32768];  // exactly 40 KB -> 4 blocks/CU
  float* xsq    = (float*)smem;          // overlay on lA buf0 (epilogue only)
  float* rowsum = (float*)(smem + 256);  // [4][64] floats

  const int tid  = threadIdx.x;
  const int lane = tid & 63;
  const int w    = tid >> 6;        // wave id = column quarter
  const int quad = lane >> 4;
  const int l16  = lane & 15;
  const int row0 = blockIdx.x * BM;
  const int sl    = (l16 ^ (l16 >> 2)) & 3;  // swizzle term (row/col low bits)
  const int slotq = quad ^ sl;               // fragment-read chunk slot

  // ---- A staging geometry: thread -> (row ar, global chunk jga) ----
  const int ar  = tid >> 2;               // 0..63
  const int jga = tid & 3;                // which 8-float chunk of the 32-k slab
  const int sa  = (ar ^ (ar >> 2)) & 3;
  const float* xg = x + (size_t)(row0 + ar) * D_DIM + jga * 8;
  const int awoff = ar * 64 + ((jga ^ sa) * 16);  // byte offset within an lA buf

  // ---- B staging geometry: 4 global_load_lds issues/thread ----
  const u16* bsrc[4];
  #pragma unroll
  for (int i = 0; i < 4; ++i) {
    int L = i * 256 + tid;          // 16B slot index in the 16 KB tile
    int c  = L >> 2;                // cluster (column) 0..255
    int jp = L & 3;                 // slot within the column's 64B row
    int jg = jp ^ ((c ^ (c >> 2)) & 3);   // global chunk stored at this slot
    bsrc[i] = cb + (size_t)c * D_DIM + jg * 8;
  }

  f32x4 acc[4][4];
  #pragma unroll
  for (int i = 0; i < 4; ++i)
    #pragma unroll
    for (int j = 0; j < 4; ++j)
      acc[i][j] = (f32x4){0.f, 0.f, 0.f, 0.f};

  float sq = 0.f;
  float4 xr[2][2];

  // ---- prologue: B(0)->lB buf0, x(0) convert->lA buf0, x(1) reg prefetch ----
  #pragma unroll
  for (int i = 0; i < 4; ++i)
    __builtin_amdgcn_global_load_lds(
        (const __attribute__((address_space(1))) void*)bsrc[i],
        (__attribute__((address_space(3))) void*)(smem + 8192 + (i * 256 + tid) * 16),
        16, 0, 0);
  {
    float4 f0 = *(const float4*)(xg + 0);
    float4 f1 = *(const float4*)(xg + 4);
    sq += f0.x*f0.x + f0.y*f0.y + f0.z*f0.z + f0.w*f0.w
        + f1.x*f1.x + f1.y*f1.y + f1.z*f1.z + f1.w*f1.w;
    union { u16 u[8]; short8_t v; } pk;
    pk.u[0]=f2bf(f0.x); pk.u[1]=f2bf(f0.y); pk.u[2]=f2bf(f0.z); pk.u[3]=f2bf(f0.w);
    pk.u[4]=f2bf(f1.x); pk.u[5]=f2bf(f1.y); pk.u[6]=f2bf(f1.z); pk.u[7]=f2bf(f1.w);
    *(short8_t*)(smem + awoff) = pk.v;
  }
  xr[1][0] = *(const float4*)(xg + 32);
  xr[1][1] = *(const float4*)(xg + 36);

  // ---- pipelined K-loop: ONE barrier per iteration ----
  #pragma unroll
  for (int kk16 = 0; kk16 < NITER; ++kk16) {
    const int b  = kk16 & 1;
    const int kk = kk16 * 32;
    __syncthreads();   // drains: B(kk) vmcnt (issued last iter), lA(kk) lgkm, bufs free

    if (kk16 < NITER - 1) {            // issue B(kk+1) -> other buf (full iter to land)
      #pragma unroll
      for (int i = 0; i < 4; ++i)
        __builtin_amdgcn_global_load_lds(
            (const __attribute__((address_space(1))) void*)(bsrc[i] + kk + 32),
            (__attribute__((address_space(3))) void*)
                (smem + 8192 + (b ^ 1) * 16384 + (i * 256 + tid) * 16),
            16, 0, 0);
    }
    if (kk16 < NITER - 2) {            // x(kk+2) reg prefetch (full iter to land)
      xr[b][0] = *(const float4*)(xg + kk + 64);
      xr[b][1] = *(const float4*)(xg + kk + 68);
    }

    // fragments (swizzled slots -> 2-way banks) + 16 MFMA
    short8_t aF[4], bF[4];
    #pragma unroll
    for (int mi = 0; mi < 4; ++mi)
      aF[mi] = *(const short8_t*)(smem + b * 4096 + mi * 1024 + l16 * 64 + slotq * 16);
    #pragma unroll
    for (int ni = 0; ni < 4; ++ni)
      bF[ni] = *(const short8_t*)(smem + 8192 + b * 16384 + w * 4096 + ni * 1024
                                  + l16 * 64 + slotq * 16);
    #pragma unroll
    for (int mi = 0; mi < 4; ++mi)
      #pragma unroll
      for (int ni = 0; ni < 4; ++ni)
        acc[mi][ni] = __builtin_amdgcn_mfma_f32_16x16x32_bf16(
            aF[mi], bF[ni], acc[mi][ni], 0, 0, 0);

    // late convert of x(kk+1) -> lA other buf (its load had a full iter already)
    if (kk16 < NITER - 1) {
      float4 f0 = xr[b ^ 1][0];
      float4 f1 = xr[b ^ 1][1];
      sq += f0.x*f0.x + f0.y*f0.y + f0.z*f0.z + f0.w*f0.w
          + f1.x*f1.x + f1.y*f1.y + f1.z*f1.z + f1.w*f1.w;
      union { u16 u[8]; short8_t v; } pk;
      pk.u[0]=f2bf(f0.x); pk.u[1]=f2bf(f0.y); pk.u[2]=f2bf(f0.z); pk.u[3]=f2bf(f0.w);
      pk.u[4]=f2bf(f1.x); pk.u[5]=f2bf(f1.y); pk.u[6]=f2bf(f1.z); pk.u[7]=f2bf(f1.w);
      *(short8_t*)(smem + (b ^ 1) * 4096 + awoff) = pk.v;
    }
  }

  // ---- x_sq: combine the 4 staging lanes of each row, stash in overlay ----
  sq += __shfl_xor(sq, 1, 64);
  sq += __shfl_xor(sq, 2, 64);
  if ((tid & 3) == 0) xsq[ar] = sq;   // overlay on lA buf0: not read in last iter
  __syncthreads();

  // per-lane cluster norms for this wave's 4 column groups
  float cs[4];
  #pragma unroll
  for (int ni = 0; ni < 4; ++ni) cs[ni] = csq[w * 64 + ni * 16 + l16];

  // ---- epilogue: Student-t + per-row partial sums ----
  #pragma unroll
  for (int mi = 0; mi < 4; ++mi) {
    #pragma unroll
    for (int v = 0; v < 4; ++v) {
      int row = mi * 16 + quad * 4 + v;
      float xs = xsq[row];
      float s = 0.f;
      #pragma unroll
      for (int ni = 0; ni < 4; ++ni) {
        float d = xs + cs[ni] - 2.0f * acc[mi][ni][v];
        d = fmaxf(d, 0.f);
        float q = 1.0f / (1.0f + d);   // alpha=1: (1+d^2)^-1
        acc[mi][ni][v] = q;
        s += q;
      }
      s += __shfl_xor(s, 1, 64);
      s += __shfl_xor(s, 2, 64);
      s += __shfl_xor(s, 4, 64);
      s += __shfl_xor(s, 8, 64);
      if (l16 == 0) rowsum[w * 64 + row] = s;
    }
  }
  __syncthreads();

  // ---- normalize + store ----
  #pragma unroll
  for (int mi = 0; mi < 4; ++mi) {
    #pragma unroll
    for (int v = 0; v < 4; ++v) {
      int row = mi * 16 + quad * 4 + v;
      float tot = rowsum[row] + rowsum[64 + row] + rowsum[128 + row] + rowsum[192 + row];
      float inv = 1.0f / tot;
      float* orow = out + (size_t)(row0 + row) * K_CL;
      #pragma unroll
      for (int ni = 0; ni < 4; ++ni)
        orow[w * 64 + ni * 16 + l16] = acc[mi][ni][v] * inv;
    }
  }
}

extern "C" void kernel_launch(void* const* d_in, const int* in_sizes, int n_in,
                              void* d_out, int out_size, void* d_ws, size_t ws_size,
                              hipStream_t stream) {
  const float* x        = (const float*)d_in[0];
  const float* clusters = (const float*)d_in[1];
  float* out = (float*)d_out;
  const int N = in_sizes[0] / D_DIM;   // 65536

  u16*   cb  = (u16*)d_ws;                                   // 256 KB
  float* csq = (float*)((char*)d_ws + (size_t)K_CL * D_DIM * sizeof(u16));

  prep_kernel<<<K_CL, 128, 0, stream>>>(clusters, cb, csq);
  cluster_kernel<<<N / BM, 256, 0, stream>>>(x, cb, csq, out);
}